// Round 1
// baseline (1250.189 us; speedup 1.0000x reference)
//
#include <hip/hip_runtime.h>
#include <stdint.h>

typedef unsigned short u16;
typedef short short8 __attribute__((ext_vector_type(8)));
typedef short short4v __attribute__((ext_vector_type(4)));
typedef float f32x4 __attribute__((ext_vector_type(4)));

#define T_TOK 2048
#define H_DIM 2048
#define E_NUM 8
#define I_DIM 4096
#define BM 256
#define MAXTILES 24   // sum_e ceil(cnt_e/256) <= 4096/256 + 7 = 23

__device__ __forceinline__ u16 f2bf(float f) {
    union { float f; uint32_t u; } v; v.f = f;
    uint32_t u = v.u;
    u += 0x7fffu + ((u >> 16) & 1u);   // round-to-nearest-even
    return (u16)(u >> 16);
}

__device__ __forceinline__ float gelu_tanh(float x) {
    // jax.nn.gelu default (approximate=True)
    float t = tanhf(0.7978845608028654f * (x + 0.044715f * x * x * x));
    return 0.5f * x * (1.0f + t);
}

// ---------------- router: logits -> softcap -> softmax -> top2; also x -> bf16
__global__ void router_kernel(const float* __restrict__ hid, const float* __restrict__ gw,
                              u16* __restrict__ xbf, int* __restrict__ tidx,
                              float* __restrict__ tw, int* __restrict__ cnt) {
    int tid = threadIdx.x;
    int wv = tid >> 6, lane = tid & 63;
    int t = blockIdx.x * 4 + wv;
    const float* xrow = hid + (size_t)t * H_DIM;
    float acc[8];
#pragma unroll
    for (int e = 0; e < 8; e++) acc[e] = 0.f;
    for (int h0 = 0; h0 < H_DIM; h0 += 64) {
        float x = xrow[h0 + lane];
        xbf[(size_t)t * H_DIM + h0 + lane] = f2bf(x);
        const float4* g4 = (const float4*)(gw + (size_t)(h0 + lane) * 8);
        float4 ga = g4[0], gb = g4[1];
        acc[0] += x * ga.x; acc[1] += x * ga.y; acc[2] += x * ga.z; acc[3] += x * ga.w;
        acc[4] += x * gb.x; acc[5] += x * gb.y; acc[6] += x * gb.z; acc[7] += x * gb.w;
    }
#pragma unroll
    for (int off = 32; off > 0; off >>= 1) {
#pragma unroll
        for (int e = 0; e < 8; e++) acc[e] += __shfl_down(acc[e], off);
    }
    if (lane == 0) {
        float l[8], p[8];
        float mx = -1e30f;
#pragma unroll
        for (int e = 0; e < 8; e++) { l[e] = 30.0f * tanhf(acc[e] * (1.0f / 30.0f)); mx = fmaxf(mx, l[e]); }
        float s = 0.f;
#pragma unroll
        for (int e = 0; e < 8; e++) { p[e] = expf(l[e] - mx); s += p[e]; }
        int i1 = 0;
#pragma unroll
        for (int e = 1; e < 8; e++) if (l[e] > l[i1]) i1 = e;   // ties -> lower index
        int i2 = (i1 == 0) ? 1 : 0;
#pragma unroll
        for (int e = 0; e < 8; e++) if (e != i1 && l[e] > l[i2]) i2 = e;
        float inv = 1.0f / s;
        tidx[2 * t] = i1;     tw[2 * t] = p[i1] * inv;      // softmax over ALL experts, no renorm
        tidx[2 * t + 1] = i2; tw[2 * t + 1] = p[i2] * inv;
        atomicAdd(&cnt[i1], 1);
        atomicAdd(&cnt[i2], 1);
    }
}

// ---------------- serial scan over 8 experts -> segment offsets + tile table
__global__ void scan_kernel(const int* __restrict__ cnt, int* seg, int* cur,
                            int* tE, int* tM0, int* tEnd) {
    if (threadIdx.x != 0) return;
    int off = 0, nt = 0;
    for (int e = 0; e < 8; e++) {
        seg[e] = off; cur[e] = off;
        int c = cnt[e];
        for (int m = 0; m < c; m += BM) { tE[nt] = e; tM0[nt] = off + m; tEnd[nt] = off + c; nt++; }
        off += c;
    }
    seg[8] = off;
    for (; nt < MAXTILES; nt++) tE[nt] = -1;
}

// ---------------- scatter (token,k) pairs into expert-grouped lists
__global__ void scatter_kernel(const int* __restrict__ tidx, const float* __restrict__ tw,
                               int* __restrict__ cur, int* __restrict__ ptok,
                               float* __restrict__ pwt) {
    int t = blockIdx.x * blockDim.x + threadIdx.x;
    if (t >= T_TOK) return;
#pragma unroll
    for (int k = 0; k < 2; k++) {
        int e = tidx[2 * t + k];
        int pos = atomicAdd(&cur[e], 1);
        ptok[pos] = t;
        pwt[pos] = tw[2 * t + k];
    }
}

// ---------------- GEMM1: Aact[p, i] = gelu(X W_gate) * (X W_up), gathered rows, bf16 out
// block tile 256x128, 512 threads = 8 waves (4m x 2n), wave tile 64x64, dual acc
__global__ __launch_bounds__(512, 2)
void gemm1_kernel(const u16* __restrict__ xbf, const float* __restrict__ wg_all,
                  const float* __restrict__ wu_all, u16* __restrict__ Aact,
                  const int* __restrict__ tE, const int* __restrict__ tM0,
                  const int* __restrict__ tEnd, const int* __restrict__ ptok) {
    int e = tE[blockIdx.x];
    if (e < 0) return;
    int m0 = tM0[blockIdx.x], mend = tEnd[blockIdx.x];
    int n0 = blockIdx.y * 128;
    __shared__ __align__(16) u16 As[256 * 40];
    __shared__ __align__(16) u16 Bgs[128 * 40];
    __shared__ __align__(16) u16 Bus[128 * 40];
    __shared__ int ltok[256];
    int tid = threadIdx.x;
    if (tid < 256) { int p = m0 + tid; ltok[tid] = (p < mend) ? ptok[p] : ptok[m0]; }
    __syncthreads();

    // A staging: 2 x uint4 per thread (256 rows x 32 k bf16)
    int ar0 = tid >> 2, ac = (tid & 3) * 8;
    int ar1 = (tid + 512) >> 2;
    const u16* arow0 = xbf + (size_t)ltok[ar0] * H_DIM;
    const u16* arow1 = xbf + (size_t)ltok[ar1] * H_DIM;
    // B staging: half the threads gate, half up; each: 8k x 2n fp32 -> bf16 -> LDS [n][k]
    int half = tid >> 8, tt = tid & 255;
    int bn = (tt & 63) * 2, bk = (tt >> 6) * 8;
    const float* bsrc = (half ? wu_all : wg_all) + (size_t)e * H_DIM * I_DIM + n0 + bn;
    u16* bdst = half ? Bus : Bgs;

    int wv = tid >> 6, lane = tid & 63, q = lane >> 4, ln = lane & 15;
    int wm = (wv & 3) * 64, wn = (wv >> 2) * 64;
    const f32x4 z4 = {0.f, 0.f, 0.f, 0.f};
    f32x4 accG[4][4], accU[4][4];
#pragma unroll
    for (int mi = 0; mi < 4; mi++)
#pragma unroll
        for (int ni = 0; ni < 4; ni++) { accG[mi][ni] = z4; accU[mi][ni] = z4; }

    for (int k0 = 0; k0 < H_DIM; k0 += 32) {
        *(uint4*)&As[ar0 * 40 + ac] = *(const uint4*)(arow0 + k0 + ac);
        *(uint4*)&As[ar1 * 40 + ac] = *(const uint4*)(arow1 + k0 + ac);
        const float* bp = bsrc + (size_t)(k0 + bk) * I_DIM;
        float2 v[8];
#pragma unroll
        for (int j = 0; j < 8; j++) v[j] = *(const float2*)(bp + (size_t)j * I_DIM);
        short8 r0, r1;
#pragma unroll
        for (int j = 0; j < 8; j++) { r0[j] = (short)f2bf(v[j].x); r1[j] = (short)f2bf(v[j].y); }
        *(short8*)&bdst[bn * 40 + bk] = r0;
        *(short8*)&bdst[(bn + 1) * 40 + bk] = r1;
        __syncthreads();

        short8 af[4], bg[4], bu[4];
#pragma unroll
        for (int mi = 0; mi < 4; mi++) af[mi] = *(const short8*)&As[(wm + mi * 16 + ln) * 40 + q * 8];
#pragma unroll
        for (int ni = 0; ni < 4; ni++) {
            bg[ni] = *(const short8*)&Bgs[(wn + ni * 16 + ln) * 40 + q * 8];
            bu[ni] = *(const short8*)&Bus[(wn + ni * 16 + ln) * 40 + q * 8];
        }
#pragma unroll
        for (int mi = 0; mi < 4; mi++)
#pragma unroll
            for (int ni = 0; ni < 4; ni++) {
                accG[mi][ni] = __builtin_amdgcn_mfma_f32_16x16x32_bf16(af[mi], bg[ni], accG[mi][ni], 0, 0, 0);
                accU[mi][ni] = __builtin_amdgcn_mfma_f32_16x16x32_bf16(af[mi], bu[ni], accU[mi][ni], 0, 0, 0);
            }
        __syncthreads();
    }
    // epilogue: act = gelu(g) * u -> bf16
#pragma unroll
    for (int mi = 0; mi < 4; mi++) {
        int pb = m0 + wm + mi * 16 + q * 4;
#pragma unroll
        for (int r = 0; r < 4; r++) {
            int p = pb + r;
            if (p < mend) {
                u16* orow = Aact + (size_t)p * I_DIM + n0 + wn;
#pragma unroll
                for (int ni = 0; ni < 4; ni++) {
                    float g = accG[mi][ni][r], u = accU[mi][ni][r];
                    orow[ni * 16 + ln] = f2bf(gelu_tanh(g) * u);
                }
            }
        }
    }
}

// ---------------- GEMM2: Y = Aact @ W_down, scale by pair weight, atomicAdd into out
// block tile 256x128, 1024 threads = 16 waves (4m x 4n), wave tile 64x32
__global__ __launch_bounds__(1024, 4)
void gemm2_kernel(const u16* __restrict__ Aact, const float* __restrict__ wd_all,
                  float* __restrict__ out, const int* __restrict__ tE,
                  const int* __restrict__ tM0, const int* __restrict__ tEnd,
                  const int* __restrict__ ptok, const float* __restrict__ pwt) {
    int e = tE[blockIdx.x];
    if (e < 0) return;
    int m0 = tM0[blockIdx.x], mend = tEnd[blockIdx.x];
    int n0 = blockIdx.y * 128;
    __shared__ __align__(16) u16 As[256 * 40];
    __shared__ __align__(16) u16 Bs[128 * 40];
    __shared__ int ltok[256];
    __shared__ float lwt[256];
    int tid = threadIdx.x;
    if (tid < 256) {
        int p = m0 + tid; bool vld = p < mend;
        ltok[tid] = vld ? ptok[p] : 0;
        lwt[tid] = vld ? pwt[p] : 0.f;
    }
    int ar = tid >> 2, ac = (tid & 3) * 8;
    const u16* asrc = Aact + (size_t)(m0 + ar) * I_DIM + ac;
    int bn = tid & 127, kq = (tid >> 7) * 4;
    const float* bsrc = wd_all + (size_t)e * I_DIM * H_DIM + (size_t)kq * H_DIM + n0 + bn;
    int wv = tid >> 6, lane = tid & 63, q = lane >> 4, ln = lane & 15;
    int wm = (wv & 3) * 64, wn = (wv >> 2) * 32;
    const f32x4 z4 = {0.f, 0.f, 0.f, 0.f};
    f32x4 acc[4][2];
#pragma unroll
    for (int mi = 0; mi < 4; mi++) { acc[mi][0] = z4; acc[mi][1] = z4; }
    __syncthreads();

    for (int k0 = 0; k0 < I_DIM; k0 += 32) {
        *(uint4*)&As[ar * 40 + ac] = *(const uint4*)(asrc + k0);
        const float* bp = bsrc + (size_t)k0 * H_DIM;
        short4v bv;
#pragma unroll
        for (int j = 0; j < 4; j++) bv[j] = (short)f2bf(bp[(size_t)j * H_DIM]);
        *(short4v*)&Bs[bn * 40 + kq] = bv;
        __syncthreads();

        short8 af[4], bf2[2];
#pragma unroll
        for (int mi = 0; mi < 4; mi++) af[mi] = *(const short8*)&As[(wm + mi * 16 + ln) * 40 + q * 8];
#pragma unroll
        for (int ni = 0; ni < 2; ni++) bf2[ni] = *(const short8*)&Bs[(wn + ni * 16 + ln) * 40 + q * 8];
#pragma unroll
        for (int mi = 0; mi < 4; mi++)
#pragma unroll
            for (int ni = 0; ni < 2; ni++)
                acc[mi][ni] = __builtin_amdgcn_mfma_f32_16x16x32_bf16(af[mi], bf2[ni], acc[mi][ni], 0, 0, 0);
        __syncthreads();
    }
#pragma unroll
    for (int mi = 0; mi < 4; mi++)
#pragma unroll
        for (int r = 0; r < 4; r++) {
            int rl = wm + mi * 16 + q * 4 + r;
            int p = m0 + rl;
            if (p < mend) {
                int tok = ltok[rl];
                float w = lwt[rl];
                float* ob = out + (size_t)tok * H_DIM + n0 + wn;
#pragma unroll
                for (int ni = 0; ni < 2; ni++)
                    atomicAdd(ob + ni * 16 + ln, acc[mi][ni][r] * w);
            }
        }
}

extern "C" void kernel_launch(void* const* d_in, const int* in_sizes, int n_in,
                              void* d_out, int out_size, void* d_ws, size_t ws_size,
                              hipStream_t stream) {
    (void)in_sizes; (void)n_in; (void)out_size; (void)ws_size;
    const float* hid = (const float*)d_in[0];
    const float* gw  = (const float*)d_in[1];
    const float* wg  = (const float*)d_in[2];
    const float* wu  = (const float*)d_in[3];
    const float* wd  = (const float*)d_in[4];
    float* out = (float*)d_out;

    char* ws = (char*)d_ws;
    size_t off = 0;
    u16* xbf  = (u16*)(ws + off); off += (size_t)T_TOK * H_DIM * 2;          // 8 MB
    u16* Aact = (u16*)(ws + off); off += (size_t)(2 * T_TOK + BM) * I_DIM * 2; // 35.7 MB (padded rows)
    int*   ptok = (int*)(ws + off);   off += 2 * T_TOK * 4;
    float* pwt  = (float*)(ws + off); off += 2 * T_TOK * 4;
    int*   tidx = (int*)(ws + off);   off += 2 * T_TOK * 4;
    float* tw   = (float*)(ws + off); off += 2 * T_TOK * 4;
    int* cnt  = (int*)(ws + off); off += 64;
    int* cur  = (int*)(ws + off); off += 64;
    int* seg  = (int*)(ws + off); off += 64;
    int* tE   = (int*)(ws + off); off += 128;
    int* tM0  = (int*)(ws + off); off += 128;
    int* tEnd = (int*)(ws + off); off += 128;

    hipMemsetAsync(cnt, 0, 64, stream);
    hipMemsetAsync(d_out, 0, (size_t)T_TOK * H_DIM * 4, stream);
    router_kernel<<<T_TOK / 4, 256, 0, stream>>>(hid, gw, xbf, tidx, tw, cnt);
    scan_kernel<<<1, 1, 0, stream>>>(cnt, seg, cur, tE, tM0, tEnd);
    scatter_kernel<<<T_TOK / 256, 256, 0, stream>>>(tidx, tw, cur, ptok, pwt);
    gemm1_kernel<<<dim3(MAXTILES, I_DIM / 128), 512, 0, stream>>>(xbf, wg, wu, Aact, tE, tM0, tEnd, ptok);
    gemm2_kernel<<<dim3(MAXTILES, H_DIM / 128), 1024, 0, stream>>>(Aact, wd, out, tE, tM0, tEnd, ptok, pwt);
}

// Round 2
// 1207.826 us; speedup vs baseline: 1.0351x; 1.0351x over previous
//
#include <hip/hip_runtime.h>
#include <stdint.h>

typedef unsigned short u16;
typedef short short8 __attribute__((ext_vector_type(8)));
typedef float f32x4 __attribute__((ext_vector_type(4)));

#define T_TOK 2048
#define H_DIM 2048
#define E_NUM 8
#define I_DIM 4096
#define BM 256
#define MAXTILES 24   // sum_e ceil(cnt_e/256) <= 4096/256 + 7 = 23

__device__ __forceinline__ u16 f2bf(float f) {
    union { float f; uint32_t u; } v; v.f = f;
    uint32_t u = v.u;
    u += 0x7fffu + ((u >> 16) & 1u);   // round-to-nearest-even
    return (u16)(u >> 16);
}

__device__ __forceinline__ float gelu_tanh(float x) {
    // jax.nn.gelu approximate=True; overflow-stable tanh via exp(-2|z|)
    float z = 0.7978845608028654f * (x + 0.044715f * x * x * x);
    float a = fabsf(z);
    float em = __expf(-2.0f * a);
    float th = (1.0f - em) / (1.0f + em);
    th = copysignf(th, z);
    return 0.5f * x * (1.0f + th);
}

// ---------------- router: logits -> softcap -> softmax -> top2; also x -> bf16
__global__ void router_kernel(const float* __restrict__ hid, const float* __restrict__ gw,
                              u16* __restrict__ xbf, int* __restrict__ tidx,
                              float* __restrict__ tw, int* __restrict__ cnt) {
    int tid = threadIdx.x;
    int wv = tid >> 6, lane = tid & 63;
    int t = blockIdx.x * 4 + wv;
    const float* xrow = hid + (size_t)t * H_DIM;
    float acc[8];
#pragma unroll
    for (int e = 0; e < 8; e++) acc[e] = 0.f;
    for (int h0 = 0; h0 < H_DIM; h0 += 64) {
        float x = xrow[h0 + lane];
        xbf[(size_t)t * H_DIM + h0 + lane] = f2bf(x);
        const float4* g4 = (const float4*)(gw + (size_t)(h0 + lane) * 8);
        float4 ga = g4[0], gb = g4[1];
        acc[0] += x * ga.x; acc[1] += x * ga.y; acc[2] += x * ga.z; acc[3] += x * ga.w;
        acc[4] += x * gb.x; acc[5] += x * gb.y; acc[6] += x * gb.z; acc[7] += x * gb.w;
    }
#pragma unroll
    for (int off = 32; off > 0; off >>= 1) {
#pragma unroll
        for (int e = 0; e < 8; e++) acc[e] += __shfl_down(acc[e], off);
    }
    if (lane == 0) {
        float l[8], p[8];
        float mx = -1e30f;
#pragma unroll
        for (int e = 0; e < 8; e++) { l[e] = 30.0f * tanhf(acc[e] * (1.0f / 30.0f)); mx = fmaxf(mx, l[e]); }
        float s = 0.f;
#pragma unroll
        for (int e = 0; e < 8; e++) { p[e] = expf(l[e] - mx); s += p[e]; }
        int i1 = 0;
#pragma unroll
        for (int e = 1; e < 8; e++) if (l[e] > l[i1]) i1 = e;   // ties -> lower index
        int i2 = (i1 == 0) ? 1 : 0;
#pragma unroll
        for (int e = 0; e < 8; e++) if (e != i1 && l[e] > l[i2]) i2 = e;
        float inv = 1.0f / s;
        tidx[2 * t] = i1;     tw[2 * t] = p[i1] * inv;      // softmax over ALL experts, no renorm
        tidx[2 * t + 1] = i2; tw[2 * t + 1] = p[i2] * inv;
        atomicAdd(&cnt[i1], 1);
        atomicAdd(&cnt[i2], 1);
    }
}

// ---------------- serial scan over 8 experts -> segment offsets + tile table
__global__ void scan_kernel(const int* __restrict__ cnt, int* seg, int* cur,
                            int* tE, int* tM0, int* tEnd) {
    if (threadIdx.x != 0) return;
    int off = 0, nt = 0;
    for (int e = 0; e < 8; e++) {
        seg[e] = off; cur[e] = off;
        int c = cnt[e];
        for (int m = 0; m < c; m += BM) { tE[nt] = e; tM0[nt] = off + m; tEnd[nt] = off + c; nt++; }
        off += c;
    }
    seg[8] = off;
    for (; nt < MAXTILES; nt++) tE[nt] = -1;
}

// ---------------- scatter (token,k) pairs into expert-grouped lists
__global__ void scatter_kernel(const int* __restrict__ tidx, const float* __restrict__ tw,
                               int* __restrict__ cur, int* __restrict__ ptok,
                               float* __restrict__ pwt) {
    int t = blockIdx.x * blockDim.x + threadIdx.x;
    if (t >= T_TOK) return;
#pragma unroll
    for (int k = 0; k < 2; k++) {
        int e = tidx[2 * t + k];
        int pos = atomicAdd(&cur[e], 1);
        ptok[pos] = t;
        pwt[pos] = tw[2 * t + k];
    }
}

// ---------------- GEMM1: Aact[p, i] = gelu(X W_gate) * (X W_up), gathered rows, bf16 out
// block tile 256x128, 512 threads = 8 waves (4m x 2n), wave tile 64x64 dual acc
// register-prefetched global loads; staging maps lane->row (bank stride 20 = 2-way free)
__global__ __launch_bounds__(512, 2)
void gemm1_kernel(const u16* __restrict__ xbf, const float* __restrict__ wg_all,
                  const float* __restrict__ wu_all, u16* __restrict__ Aact,
                  const int* __restrict__ tE, const int* __restrict__ tM0,
                  const int* __restrict__ tEnd, const int* __restrict__ ptok) {
    int e = tE[blockIdx.x];
    if (e < 0) return;
    int m0 = tM0[blockIdx.x], mend = tEnd[blockIdx.x];
    int n0 = blockIdx.y * 128;
    __shared__ __align__(16) u16 As[256 * 40];
    __shared__ __align__(16) u16 Bgs[128 * 40];
    __shared__ __align__(16) u16 Bus[128 * 40];
    __shared__ int ltok[256];
    int tid = threadIdx.x;
    if (tid < 256) { int p = m0 + tid; ltok[tid] = (p < mend) ? ptok[p] : ptok[m0]; }
    __syncthreads();

    // A staging: lane -> row (tid&255), two 16B chunks at col (tid>>8)*16
    int arow = tid & 255;
    int acol = (tid >> 8) * 16;
    const u16* aptr = xbf + (size_t)ltok[arow] * H_DIM + acol;
    u16* asd = &As[arow * 40 + acol];
    // B staging: halves gate/up; within half: row n = tt&127, k-chunk kh = (tt>>7)*16
    int half = tid >> 8, tt = tid & 255;
    int bn = tt & 127;
    int bkh = (tt >> 7) * 16;
    const float* bptr = (half ? wu_all : wg_all) + (size_t)e * H_DIM * I_DIM + n0 + bn;
    u16* bsd = (half ? Bus : Bgs) + bn * 40 + bkh;

    int wv = tid >> 6, lane = tid & 63, q = lane >> 4, ln = lane & 15;
    int wm = (wv & 3) * 64, wn = (wv >> 2) * 64;
    const f32x4 z4 = {0.f, 0.f, 0.f, 0.f};
    f32x4 accG[4][4], accU[4][4];
#pragma unroll
    for (int mi = 0; mi < 4; mi++)
#pragma unroll
        for (int ni = 0; ni < 4; ni++) { accG[mi][ni] = z4; accU[mi][ni] = z4; }

    // prefetch k0 = 0
    uint4 pa0 = *(const uint4*)(aptr);
    uint4 pa1 = *(const uint4*)(aptr + 8);
    float pb[16];
#pragma unroll
    for (int j = 0; j < 16; j++) pb[j] = bptr[(size_t)(bkh + j) * I_DIM];

    for (int k0 = 0; k0 < H_DIM; k0 += 32) {
        // drain prefetched regs into LDS
        *(uint4*)asd = pa0;
        *(uint4*)(asd + 8) = pa1;
        short8 r0, r1;
#pragma unroll
        for (int j = 0; j < 8; j++) { r0[j] = (short)f2bf(pb[j]); r1[j] = (short)f2bf(pb[8 + j]); }
        *(short8*)bsd = r0;
        *(short8*)(bsd + 8) = r1;
        // issue next k-slice loads; they complete during the MFMA phase below
        if (k0 + 32 < H_DIM) {
            pa0 = *(const uint4*)(aptr + k0 + 32);
            pa1 = *(const uint4*)(aptr + k0 + 32 + 8);
            const float* bp2 = bptr + (size_t)(k0 + 32 + bkh) * I_DIM;
#pragma unroll
            for (int j = 0; j < 16; j++) pb[j] = bp2[(size_t)j * I_DIM];
        }
        __syncthreads();

        short8 af[4], bg[4], bu[4];
#pragma unroll
        for (int mi = 0; mi < 4; mi++) af[mi] = *(const short8*)&As[(wm + mi * 16 + ln) * 40 + q * 8];
#pragma unroll
        for (int ni = 0; ni < 4; ni++) {
            bg[ni] = *(const short8*)&Bgs[(wn + ni * 16 + ln) * 40 + q * 8];
            bu[ni] = *(const short8*)&Bus[(wn + ni * 16 + ln) * 40 + q * 8];
        }
#pragma unroll
        for (int mi = 0; mi < 4; mi++)
#pragma unroll
            for (int ni = 0; ni < 4; ni++) {
                accG[mi][ni] = __builtin_amdgcn_mfma_f32_16x16x32_bf16(af[mi], bg[ni], accG[mi][ni], 0, 0, 0);
                accU[mi][ni] = __builtin_amdgcn_mfma_f32_16x16x32_bf16(af[mi], bu[ni], accU[mi][ni], 0, 0, 0);
            }
        __syncthreads();
    }
    // epilogue: act = gelu(g) * u -> bf16
#pragma unroll
    for (int mi = 0; mi < 4; mi++) {
        int pb2 = m0 + wm + mi * 16 + q * 4;
#pragma unroll
        for (int r = 0; r < 4; r++) {
            int p = pb2 + r;
            if (p < mend) {
                u16* orow = Aact + (size_t)p * I_DIM + n0 + wn;
#pragma unroll
                for (int ni = 0; ni < 4; ni++) {
                    float g = accG[mi][ni][r], u = accU[mi][ni][r];
                    orow[ni * 16 + ln] = f2bf(gelu_tanh(g) * u);
                }
            }
        }
    }
}

// ---------------- GEMM2: Y = Aact @ W_down, scale by pair weight, atomicAdd into out
// block tile 256x128, 512 threads = 8 waves (4m x 2n), wave tile 64x64, prefetched
__global__ __launch_bounds__(512, 2)
void gemm2_kernel(const u16* __restrict__ Aact, const float* __restrict__ wd_all,
                  float* __restrict__ out, const int* __restrict__ tE,
                  const int* __restrict__ tM0, const int* __restrict__ tEnd,
                  const int* __restrict__ ptok, const float* __restrict__ pwt) {
    int e = tE[blockIdx.x];
    if (e < 0) return;
    int m0 = tM0[blockIdx.x], mend = tEnd[blockIdx.x];
    int n0 = blockIdx.y * 128;
    __shared__ __align__(16) u16 As[256 * 40];
    __shared__ __align__(16) u16 Bs[128 * 40];
    __shared__ int ltok[256];
    __shared__ float lwt[256];
    int tid = threadIdx.x;
    if (tid < 256) {
        int p = m0 + tid; bool vld = p < mend;
        ltok[tid] = vld ? ptok[p] : 0;
        lwt[tid] = vld ? pwt[p] : 0.f;
    }
    // A staging: lane -> row, two 16B chunks
    int arow = tid & 255;
    int acol = (tid >> 8) * 16;
    const u16* aptr = Aact + (size_t)(m0 + arow) * I_DIM + acol;
    u16* asd = &As[arow * 40 + acol];
    // B staging: row n = tid&127, k-chunk kh = (tid>>7)*8
    int bn = tid & 127;
    int bkh = (tid >> 7) * 8;
    const float* bptr = wd_all + (size_t)e * I_DIM * H_DIM + n0 + bn;
    u16* bsd = &Bs[bn * 40 + bkh];

    int wv = tid >> 6, lane = tid & 63, q = lane >> 4, ln = lane & 15;
    int wm = (wv & 3) * 64, wn = (wv >> 2) * 64;
    const f32x4 z4 = {0.f, 0.f, 0.f, 0.f};
    f32x4 acc[4][4];
#pragma unroll
    for (int mi = 0; mi < 4; mi++)
#pragma unroll
        for (int ni = 0; ni < 4; ni++) acc[mi][ni] = z4;

    uint4 pa0 = *(const uint4*)(aptr);
    uint4 pa1 = *(const uint4*)(aptr + 8);
    float pb[8];
#pragma unroll
    for (int j = 0; j < 8; j++) pb[j] = bptr[(size_t)(bkh + j) * H_DIM];
    __syncthreads();

    for (int k0 = 0; k0 < I_DIM; k0 += 32) {
        *(uint4*)asd = pa0;
        *(uint4*)(asd + 8) = pa1;
        short8 r0;
#pragma unroll
        for (int j = 0; j < 8; j++) r0[j] = (short)f2bf(pb[j]);
        *(short8*)bsd = r0;
        if (k0 + 32 < I_DIM) {
            pa0 = *(const uint4*)(aptr + k0 + 32);
            pa1 = *(const uint4*)(aptr + k0 + 32 + 8);
            const float* bp2 = bptr + (size_t)(k0 + 32 + bkh) * H_DIM;
#pragma unroll
            for (int j = 0; j < 8; j++) pb[j] = bp2[(size_t)j * H_DIM];
        }
        __syncthreads();

        short8 af[4], bf4[4];
#pragma unroll
        for (int mi = 0; mi < 4; mi++) af[mi] = *(const short8*)&As[(wm + mi * 16 + ln) * 40 + q * 8];
#pragma unroll
        for (int ni = 0; ni < 4; ni++) bf4[ni] = *(const short8*)&Bs[(wn + ni * 16 + ln) * 40 + q * 8];
#pragma unroll
        for (int mi = 0; mi < 4; mi++)
#pragma unroll
            for (int ni = 0; ni < 4; ni++)
                acc[mi][ni] = __builtin_amdgcn_mfma_f32_16x16x32_bf16(af[mi], bf4[ni], acc[mi][ni], 0, 0, 0);
        __syncthreads();
    }
#pragma unroll
    for (int mi = 0; mi < 4; mi++)
#pragma unroll
        for (int r = 0; r < 4; r++) {
            int rl = wm + mi * 16 + q * 4 + r;
            int p = m0 + rl;
            if (p < mend) {
                int tok = ltok[rl];
                float w = lwt[rl];
                float* ob = out + (size_t)tok * H_DIM + n0 + wn;
#pragma unroll
                for (int ni = 0; ni < 4; ni++)
                    atomicAdd(ob + ni * 16 + ln, acc[mi][ni][r] * w);
            }
        }
}

extern "C" void kernel_launch(void* const* d_in, const int* in_sizes, int n_in,
                              void* d_out, int out_size, void* d_ws, size_t ws_size,
                              hipStream_t stream) {
    (void)in_sizes; (void)n_in; (void)out_size; (void)ws_size;
    const float* hid = (const float*)d_in[0];
    const float* gw  = (const float*)d_in[1];
    const float* wg  = (const float*)d_in[2];
    const float* wu  = (const float*)d_in[3];
    const float* wd  = (const float*)d_in[4];
    float* out = (float*)d_out;

    char* ws = (char*)d_ws;
    size_t off = 0;
    u16* xbf  = (u16*)(ws + off); off += (size_t)T_TOK * H_DIM * 2;            // 8 MB
    u16* Aact = (u16*)(ws + off); off += (size_t)(2 * T_TOK + BM) * I_DIM * 2; // 35.7 MB (padded rows)
    int*   ptok = (int*)(ws + off);   off += 2 * T_TOK * 4;
    float* pwt  = (float*)(ws + off); off += 2 * T_TOK * 4;
    int*   tidx = (int*)(ws + off);   off += 2 * T_TOK * 4;
    float* tw   = (float*)(ws + off); off += 2 * T_TOK * 4;
    int* cnt  = (int*)(ws + off); off += 64;
    int* cur  = (int*)(ws + off); off += 64;
    int* seg  = (int*)(ws + off); off += 64;
    int* tE   = (int*)(ws + off); off += 128;
    int* tM0  = (int*)(ws + off); off += 128;
    int* tEnd = (int*)(ws + off); off += 128;

    hipMemsetAsync(cnt, 0, 64, stream);
    hipMemsetAsync(d_out, 0, (size_t)T_TOK * H_DIM * 4, stream);
    router_kernel<<<T_TOK / 4, 256, 0, stream>>>(hid, gw, xbf, tidx, tw, cnt);
    scan_kernel<<<1, 1, 0, stream>>>(cnt, seg, cur, tE, tM0, tEnd);
    scatter_kernel<<<T_TOK / 256, 256, 0, stream>>>(tidx, tw, cur, ptok, pwt);
    gemm1_kernel<<<dim3(MAXTILES, I_DIM / 128), 512, 0, stream>>>(xbf, wg, wu, Aact, tE, tM0, tEnd, ptok);
    gemm2_kernel<<<dim3(MAXTILES, H_DIM / 128), 512, 0, stream>>>(Aact, wd, out, tE, tM0, tEnd, ptok, pwt);
}